// Round 1
// baseline (485.929 us; speedup 1.0000x reference)
//
#include <hip/hip_runtime.h>
#include <hip/hip_bf16.h>
#include <math.h>

#define DIM 256
#define B_SEG 512
#define LN_EPS 1e-5f
#define CHUNK 128   // nodes per block in segsum
#define NT 32       // nodes per block in gate kernel

__device__ __forceinline__ float gelu_exact(float v) {
    return 0.5f * v * (1.0f + erff(v * 0.70710678118654752f));
}

// ---------------- Kernel 1: segment sum + counts (batch is sorted) -------------
__global__ __launch_bounds__(256) void k_segsum(const float* __restrict__ x,
                                                const int* __restrict__ batch,
                                                float* __restrict__ sums,  // [B,D]
                                                float* __restrict__ cnt,   // [B]
                                                int n) {
    int i0 = blockIdx.x * CHUNK;
    if (i0 >= n) return;
    int i1 = min(i0 + CHUNK, n);
    int d = threadIdx.x;
    float acc = 0.f;
    int cur = batch[i0];
    int run = 0;
    for (int i = i0; i < i1; ++i) {
        int b = batch[i];
        if (b != cur) {
            atomicAdd(&sums[(size_t)cur * DIM + d], acc);
            if (d == 0) atomicAdd(&cnt[cur], (float)run);
            acc = 0.f; run = 0; cur = b;
        }
        acc += x[(size_t)i * DIM + d];
        run++;
    }
    atomicAdd(&sums[(size_t)cur * DIM + d], acc);
    if (d == 0) atomicAdd(&cnt[cur], (float)run);
}

// ---------------- Kernel 2: per-segment VN pipeline ---------------------------
// one block per segment, 256 threads (= D)
__global__ __launch_bounds__(256) void k_vn(const float* __restrict__ sums,
                                            const float* __restrict__ cnt,
                                            const float* __restrict__ vn_embed,
                                            const float* __restrict__ W1, const float* __restrict__ b1,
                                            const float* __restrict__ g1, const float* __restrict__ be1,
                                            const float* __restrict__ W2, const float* __restrict__ b2,
                                            const float* __restrict__ g2, const float* __restrict__ be2,
                                            const float* __restrict__ Wg, const float* __restrict__ bg,
                                            float* __restrict__ vn_state_out, // [B,D] (d_out tail)
                                            float* __restrict__ nu,           // ws [B,D]
                                            float* __restrict__ gpart) {      // ws [B,D]
    __shared__ float sIn[DIM];
    __shared__ float sRed[DIM];
    __shared__ float sRed2[DIM];
    const int b = blockIdx.x;
    const int d = threadIdx.x;

    float c = cnt[b];
    float denom = fmaxf(c, 1.0f);
    sIn[d] = sums[(size_t)b * DIM + d] / denom;
    __syncthreads();

    // ---- h1 = gelu(agg @ W1 + b1) ----
    float h = b1[d];
    for (int k = 0; k < DIM; ++k) h = fmaf(sIn[k], W1[(size_t)k * DIM + d], h);
    h = gelu_exact(h);

    // ---- LayerNorm 1 ----
    sRed[d] = h; sRed2[d] = h * h;
    __syncthreads();
    for (int s = 128; s > 0; s >>= 1) {
        if (d < s) { sRed[d] += sRed[d + s]; sRed2[d] += sRed2[d + s]; }
        __syncthreads();
    }
    float mu = sRed[0] * (1.0f / DIM);
    float var = fmaxf(sRed2[0] * (1.0f / DIM) - mu * mu, 0.0f);
    float rs = rsqrtf(var + LN_EPS);
    float vnst = vn_embed[d] + ((h - mu) * rs * g1[d] + be1[d]);
    vn_state_out[(size_t)b * DIM + d] = vnst;
    __syncthreads();
    sIn[d] = vnst;
    __syncthreads();

    // ---- h2 = gelu(vn_state @ W2 + b2) ----
    float h2 = b2[d];
    for (int k = 0; k < DIM; ++k) h2 = fmaf(sIn[k], W2[(size_t)k * DIM + d], h2);
    h2 = gelu_exact(h2);

    // ---- LayerNorm 2 ----
    sRed[d] = h2; sRed2[d] = h2 * h2;
    __syncthreads();
    for (int s = 128; s > 0; s >>= 1) {
        if (d < s) { sRed[d] += sRed[d + s]; sRed2[d] += sRed2[d + s]; }
        __syncthreads();
    }
    float mu2 = sRed[0] * (1.0f / DIM);
    float var2 = fmaxf(sRed2[0] * (1.0f / DIM) - mu2 * mu2, 0.0f);
    float rs2 = rsqrtf(var2 + LN_EPS);
    float nud = (h2 - mu2) * rs2 * g2[d] + be2[d];
    nu[(size_t)b * DIM + d] = nud;
    __syncthreads();
    sIn[d] = nud;
    __syncthreads();

    // ---- gpart = nu @ Wg[D:2D,:] + bg ----
    float gp = bg[d];
    for (int k = 0; k < DIM; ++k) gp = fmaf(sIn[k], Wg[(size_t)(DIM + k) * DIM + d], gp);
    gpart[(size_t)b * DIM + d] = gp;
}

// ---------------- Kernel 3: gate GEMM (x @ Wg_top) + epilogue -----------------
// Block: 256 threads = 64 d-columns x 4 node-groups; each thread: 8 nodes x 4 dims
__global__ __launch_bounds__(256) void k_gate(const float* __restrict__ x,
                                              const int* __restrict__ batch,
                                              const float* __restrict__ Wg,    // [2D,D]
                                              const float* __restrict__ nu,    // [B,D]
                                              const float* __restrict__ gpart, // [B,D]
                                              float* __restrict__ xout,
                                              int n) {
    __shared__ float sX[NT][DIM];
    __shared__ int sB[NT];
    const int i0 = blockIdx.x * NT;
    const int tid = threadIdx.x;

    // load x tile (NT rows) into LDS, vectorized
    {
        const float4* xv = (const float4*)(x + (size_t)i0 * DIM);
        float4* sv = (float4*)(&sX[0][0]);
        const int nvec = NT * DIM / 4;
        for (int t = tid; t < nvec; t += 256) {
            int node = i0 + t / (DIM / 4);
            if (node < n) sv[t] = xv[t];
            else sv[t] = make_float4(0.f, 0.f, 0.f, 0.f);
        }
        if (tid < NT) sB[tid] = (i0 + tid < n) ? batch[i0 + tid] : 0;
    }
    __syncthreads();

    const int dcol = tid & 63;
    const int jbase = (tid >> 6) * 8;

    float acc[8][4];
    #pragma unroll
    for (int jj = 0; jj < 8; ++jj) {
        int bb = sB[jbase + jj];
        #pragma unroll
        for (int m = 0; m < 4; ++m)
            acc[jj][m] = gpart[(size_t)bb * DIM + dcol + 64 * m];
    }

    for (int k = 0; k < DIM; ++k) {
        float w0 = Wg[(size_t)k * DIM + dcol];
        float w1 = Wg[(size_t)k * DIM + dcol + 64];
        float w2 = Wg[(size_t)k * DIM + dcol + 128];
        float w3 = Wg[(size_t)k * DIM + dcol + 192];
        #pragma unroll
        for (int jj = 0; jj < 8; ++jj) {
            float xv = sX[jbase + jj][k];
            acc[jj][0] = fmaf(xv, w0, acc[jj][0]);
            acc[jj][1] = fmaf(xv, w1, acc[jj][1]);
            acc[jj][2] = fmaf(xv, w2, acc[jj][2]);
            acc[jj][3] = fmaf(xv, w3, acc[jj][3]);
        }
    }

    #pragma unroll
    for (int jj = 0; jj < 8; ++jj) {
        int node = i0 + jbase + jj;
        if (node >= n) continue;
        int bb = sB[jbase + jj];
        #pragma unroll
        for (int m = 0; m < 4; ++m) {
            int d = dcol + 64 * m;
            float g = 1.0f / (1.0f + expf(-acc[jj][m]));
            float nud = nu[(size_t)bb * DIM + d];
            xout[(size_t)node * DIM + d] = sX[jbase + jj][d] + g * nud;
        }
    }
}

extern "C" void kernel_launch(void* const* d_in, const int* in_sizes, int n_in,
                              void* d_out, int out_size, void* d_ws, size_t ws_size,
                              hipStream_t stream) {
    const float* x        = (const float*)d_in[0];
    const int*   batch    = (const int*)d_in[1];
    const float* vn_embed = (const float*)d_in[2];
    const float* W1  = (const float*)d_in[3];
    const float* b1  = (const float*)d_in[4];
    const float* g1  = (const float*)d_in[5];
    const float* be1 = (const float*)d_in[6];
    const float* W2  = (const float*)d_in[7];
    const float* b2  = (const float*)d_in[8];
    const float* g2  = (const float*)d_in[9];
    const float* be2 = (const float*)d_in[10];
    const float* Wg  = (const float*)d_in[11];
    const float* bg  = (const float*)d_in[12];

    const int n = in_sizes[0] / DIM;

    float* out = (float*)d_out;
    float* xout = out;                              // [N,D]
    float* vn_state_out = out + (size_t)n * DIM;    // [B,D]

    float* ws    = (float*)d_ws;
    float* sums  = ws;                                   // B*D
    float* cnt   = sums + (size_t)B_SEG * DIM;           // B
    float* nu    = cnt + B_SEG;                          // B*D
    float* gpart = nu + (size_t)B_SEG * DIM;             // B*D

    hipMemsetAsync(d_ws, 0, ((size_t)B_SEG * DIM + B_SEG) * sizeof(float), stream);

    int nblk1 = (n + CHUNK - 1) / CHUNK;
    k_segsum<<<nblk1, 256, 0, stream>>>(x, batch, sums, cnt, n);

    k_vn<<<B_SEG, 256, 0, stream>>>(sums, cnt, vn_embed,
                                    W1, b1, g1, be1,
                                    W2, b2, g2, be2,
                                    Wg, bg,
                                    vn_state_out, nu, gpart);

    int nblk3 = (n + NT - 1) / NT;
    k_gate<<<nblk3, 256, 0, stream>>>(x, batch, Wg, nu, gpart, xout, n);
}

// Round 2
// 320.445 us; speedup vs baseline: 1.5164x; 1.5164x over previous
//
#include <hip/hip_runtime.h>
#include <hip/hip_bf16.h>
#include <math.h>

#define DIM 256
#define B_SEG 512
#define LN_EPS 1e-5f
#define CHUNK 128   // nodes per block in segsum
#define BM 64       // nodes per block in gate kernel
#define BK 64       // K-step in gate kernel

typedef __attribute__((ext_vector_type(8))) short bf16x8;
typedef __attribute__((ext_vector_type(4))) float f32x4;

__device__ __forceinline__ float gelu_exact(float v) {
    return 0.5f * v * (1.0f + erff(v * 0.70710678118654752f));
}

__device__ __forceinline__ unsigned int pack2bf(float a, float b) {
    unsigned int ua = (unsigned int)__bfloat16_as_ushort(__float2bfloat16(a));
    unsigned int ub = (unsigned int)__bfloat16_as_ushort(__float2bfloat16(b));
    return ua | (ub << 16);
}

__device__ __forceinline__ void async16(const void* g, void* l) {
    __builtin_amdgcn_global_load_lds(
        (const __attribute__((address_space(1))) void*)(g),
        (__attribute__((address_space(3))) void*)(l), 16, 0, 0);
}

// ---------------- Kernel 0: transpose+convert Wg top half -> Wt[c][k] bf16 ----
__global__ __launch_bounds__(256) void k_wprep(const float* __restrict__ Wg,
                                               __hip_bfloat16* __restrict__ Wt) {
    int c = blockIdx.x;   // 0..255 (output col)
    int k = threadIdx.x;  // 0..255
    Wt[(size_t)c * DIM + k] = __float2bfloat16(Wg[(size_t)k * DIM + c]);
}

// ---------------- Kernel 1: segment sum + counts (batch is sorted) -------------
__global__ __launch_bounds__(256) void k_segsum(const float* __restrict__ x,
                                                const int* __restrict__ batch,
                                                float* __restrict__ sums,  // [B,D]
                                                float* __restrict__ cnt,   // [B]
                                                int n) {
    int i0 = blockIdx.x * CHUNK;
    if (i0 >= n) return;
    int i1 = min(i0 + CHUNK, n);
    int d = threadIdx.x;
    float acc = 0.f;
    int cur = batch[i0];
    int run = 0;
    for (int i = i0; i < i1; ++i) {
        int b = batch[i];
        if (b != cur) {
            atomicAdd(&sums[(size_t)cur * DIM + d], acc);
            if (d == 0) atomicAdd(&cnt[cur], (float)run);
            acc = 0.f; run = 0; cur = b;
        }
        acc += x[(size_t)i * DIM + d];
        run++;
    }
    atomicAdd(&sums[(size_t)cur * DIM + d], acc);
    if (d == 0) atomicAdd(&cnt[cur], (float)run);
}

// ---------------- Kernel 2: per-segment VN pipeline ---------------------------
__global__ __launch_bounds__(256) void k_vn(const float* __restrict__ sums,
                                            const float* __restrict__ cnt,
                                            const float* __restrict__ vn_embed,
                                            const float* __restrict__ W1, const float* __restrict__ b1,
                                            const float* __restrict__ g1, const float* __restrict__ be1,
                                            const float* __restrict__ W2, const float* __restrict__ b2,
                                            const float* __restrict__ g2, const float* __restrict__ be2,
                                            const float* __restrict__ Wg, const float* __restrict__ bg,
                                            float* __restrict__ vn_state_out, // [B,D]
                                            float* __restrict__ nu,           // ws [B,D]
                                            float* __restrict__ gpart) {      // ws [B,D]
    __shared__ float sIn[DIM];
    __shared__ float sRed[DIM];
    __shared__ float sRed2[DIM];
    const int b = blockIdx.x;
    const int d = threadIdx.x;

    float c = cnt[b];
    float denom = fmaxf(c, 1.0f);
    sIn[d] = sums[(size_t)b * DIM + d] / denom;
    __syncthreads();

    float h = b1[d];
    for (int k = 0; k < DIM; ++k) h = fmaf(sIn[k], W1[(size_t)k * DIM + d], h);
    h = gelu_exact(h);

    sRed[d] = h; sRed2[d] = h * h;
    __syncthreads();
    for (int s = 128; s > 0; s >>= 1) {
        if (d < s) { sRed[d] += sRed[d + s]; sRed2[d] += sRed2[d + s]; }
        __syncthreads();
    }
    float mu = sRed[0] * (1.0f / DIM);
    float var = fmaxf(sRed2[0] * (1.0f / DIM) - mu * mu, 0.0f);
    float rs = rsqrtf(var + LN_EPS);
    float vnst = vn_embed[d] + ((h - mu) * rs * g1[d] + be1[d]);
    vn_state_out[(size_t)b * DIM + d] = vnst;
    __syncthreads();
    sIn[d] = vnst;
    __syncthreads();

    float h2 = b2[d];
    for (int k = 0; k < DIM; ++k) h2 = fmaf(sIn[k], W2[(size_t)k * DIM + d], h2);
    h2 = gelu_exact(h2);

    sRed[d] = h2; sRed2[d] = h2 * h2;
    __syncthreads();
    for (int s = 128; s > 0; s >>= 1) {
        if (d < s) { sRed[d] += sRed[d + s]; sRed2[d] += sRed2[d + s]; }
        __syncthreads();
    }
    float mu2 = sRed[0] * (1.0f / DIM);
    float var2 = fmaxf(sRed2[0] * (1.0f / DIM) - mu2 * mu2, 0.0f);
    float rs2 = rsqrtf(var2 + LN_EPS);
    float nud = (h2 - mu2) * rs2 * g2[d] + be2[d];
    nu[(size_t)b * DIM + d] = nud;
    __syncthreads();
    sIn[d] = nud;
    __syncthreads();

    float gp = bg[d];
    for (int k = 0; k < DIM; ++k) gp = fmaf(sIn[k], Wg[(size_t)(DIM + k) * DIM + d], gp);
    gpart[(size_t)b * DIM + d] = gp;
}

// ---------------- Kernel 3: MFMA gate GEMM (x @ Wg_top) + epilogue ------------
// grid: n/BM blocks, 256 threads = 4 waves; wave w -> cols [w*64, w*64+64)
// LDS: double-buffered A (x tile, bf16, swizzled) + B (Wt slice, bf16, swizzled)
__global__ __launch_bounds__(256, 2) void k_gate_mfma(const float* __restrict__ x,
                                                      const int* __restrict__ batch,
                                                      const __hip_bfloat16* __restrict__ Wt, // [256c][256k]
                                                      const float* __restrict__ nu,    // [B,D]
                                                      const float* __restrict__ gpart, // [B,D]
                                                      float* __restrict__ xout,
                                                      int n) {
    __shared__ __align__(16) __hip_bfloat16 sA[2][BM * BK];   // 8 KB each
    __shared__ __align__(16) __hip_bfloat16 sB[2][DIM * BK];  // 32 KB each
    __shared__ int sBat[BM];

    const int tid  = threadIdx.x;
    const int wave = tid >> 6;
    const int lane = tid & 63;
    const int i0   = blockIdx.x * BM;

    if (tid < BM) sBat[tid] = (i0 + tid < n) ? batch[i0 + tid] : 0;

    // ---- B staging: async global->LDS, source pre-swizzled (rule #21) ----
    auto stageB = [&](int buf, int kb) {
        #pragma unroll
        for (int i = 0; i < 8; ++i) {
            int F = (wave * 8 + i) * 1024 + lane * 16;       // flat LDS byte dest (lane part implicit)
            int c = F >> 7;                                  // row (output col)
            int p = F & 127;                                 // byte pos in row
            int ps = p ^ ((c & 7) << 4);                     // pre-swizzled source pos
            const __hip_bfloat16* g = Wt + (size_t)c * DIM + kb * BK + (ps >> 1);
            char* l = (char*)(&sB[buf][0]) + (wave * 8 + i) * 1024; // wave-uniform base
            async16(g, l);
        }
    };

    // ---- A staging part 1: issue global loads (fp32) ----
    float4 av[4];
    auto loadA = [&](int kb) {
        #pragma unroll
        for (int gg = 0; gg < 2; ++gg) {
            int g = tid + gg * 256;        // 0..511
            int r = g >> 3;                // row 0..63
            int kg = g & 7;                // 8-elem k group
            int node = i0 + r;
            if (node < n) {
                const float4* p = (const float4*)(x + (size_t)node * DIM + kb * BK + kg * 8);
                av[gg * 2 + 0] = p[0];
                av[gg * 2 + 1] = p[1];
            } else {
                av[gg * 2 + 0] = make_float4(0.f, 0.f, 0.f, 0.f);
                av[gg * 2 + 1] = make_float4(0.f, 0.f, 0.f, 0.f);
            }
        }
    };
    // ---- A staging part 2: convert + swizzled ds_write ----
    auto writeA = [&](int buf) {
        #pragma unroll
        for (int gg = 0; gg < 2; ++gg) {
            int g = tid + gg * 256;
            int r = g >> 3;
            int kg = g & 7;
            uint4 pk;
            pk.x = pack2bf(av[gg * 2 + 0].x, av[gg * 2 + 0].y);
            pk.y = pack2bf(av[gg * 2 + 0].z, av[gg * 2 + 0].w);
            pk.z = pack2bf(av[gg * 2 + 1].x, av[gg * 2 + 1].y);
            pk.w = pack2bf(av[gg * 2 + 1].z, av[gg * 2 + 1].w);
            int byteoff = r * 128 + ((kg * 16) ^ ((r & 7) << 4));
            *(uint4*)((char*)(&sA[buf][0]) + byteoff) = pk;
        }
    };

    f32x4 acc[4][4];
    #pragma unroll
    for (int m = 0; m < 4; ++m)
        #pragma unroll
        for (int nn = 0; nn < 4; ++nn)
            acc[m][nn] = (f32x4){0.f, 0.f, 0.f, 0.f};

    // prologue: fill buffer 0
    stageB(0, 0);
    loadA(0);
    writeA(0);
    __syncthreads();

    for (int kb = 0; kb < 4; ++kb) {
        const int cur = kb & 1;
        const bool pf = (kb < 3);
        if (pf) {
            stageB(cur ^ 1, kb + 1);   // async loads in flight across MFMA block
            loadA(kb + 1);             // global->reg issued early (T14)
        }
        // compute on buf[cur]
        #pragma unroll
        for (int ks = 0; ks < 2; ++ks) {
            bf16x8 a[4], b[4];
            const int kbyte = ks * 64 + (lane >> 4) * 16;
            #pragma unroll
            for (int m = 0; m < 4; ++m) {
                int r = m * 16 + (lane & 15);
                a[m] = *(const bf16x8*)((const char*)(&sA[cur][0]) + r * 128 + (kbyte ^ ((r & 7) << 4)));
            }
            #pragma unroll
            for (int nn = 0; nn < 4; ++nn) {
                int c = wave * 64 + nn * 16 + (lane & 15);
                b[nn] = *(const bf16x8*)((const char*)(&sB[cur][0]) + c * 128 + (kbyte ^ ((c & 7) << 4)));
            }
            #pragma unroll
            for (int m = 0; m < 4; ++m)
                #pragma unroll
                for (int nn = 0; nn < 4; ++nn)
                    acc[m][nn] = __builtin_amdgcn_mfma_f32_16x16x32_bf16(a[m], b[nn], acc[m][nn], 0, 0, 0);
        }
        if (pf) writeA(cur ^ 1);       // reg->LDS after compute, before barrier
        __syncthreads();
    }

    // ---- epilogue: + gpart[seg], sigmoid, x + g*nu ----
    // C layout: col = lane&15, row = (lane>>4)*4 + q   [m89]
    #pragma unroll
    for (int m = 0; m < 4; ++m) {
        #pragma unroll
        for (int q = 0; q < 4; ++q) {
            int rr = m * 16 + (lane >> 4) * 4 + q;
            int node = i0 + rr;
            if (node >= n) continue;
            int bb = sBat[rr];
            #pragma unroll
            for (int nn = 0; nn < 4; ++nn) {
                int col = wave * 64 + nn * 16 + (lane & 15);
                float pre = acc[m][nn][q] + gpart[bb * DIM + col];
                float gte = 1.0f / (1.0f + expf(-pre));
                xout[(size_t)node * DIM + col] = x[(size_t)node * DIM + col] + gte * nu[bb * DIM + col];
            }
        }
    }
}

extern "C" void kernel_launch(void* const* d_in, const int* in_sizes, int n_in,
                              void* d_out, int out_size, void* d_ws, size_t ws_size,
                              hipStream_t stream) {
    const float* x        = (const float*)d_in[0];
    const int*   batch    = (const int*)d_in[1];
    const float* vn_embed = (const float*)d_in[2];
    const float* W1  = (const float*)d_in[3];
    const float* b1  = (const float*)d_in[4];
    const float* g1  = (const float*)d_in[5];
    const float* be1 = (const float*)d_in[6];
    const float* W2  = (const float*)d_in[7];
    const float* b2  = (const float*)d_in[8];
    const float* g2  = (const float*)d_in[9];
    const float* be2 = (const float*)d_in[10];
    const float* Wg  = (const float*)d_in[11];
    const float* bg  = (const float*)d_in[12];

    const int n = in_sizes[0] / DIM;

    float* out = (float*)d_out;
    float* xout = out;                              // [N,D]
    float* vn_state_out = out + (size_t)n * DIM;    // [B,D]

    float* ws    = (float*)d_ws;
    float* sums  = ws;                                   // B*D
    float* cnt   = sums + (size_t)B_SEG * DIM;           // B
    float* nu    = cnt + B_SEG;                          // B*D
    float* gpart = nu + (size_t)B_SEG * DIM;             // B*D
    __hip_bfloat16* Wt = (__hip_bfloat16*)(gpart + (size_t)B_SEG * DIM); // 256*256 bf16

    hipMemsetAsync(d_ws, 0, ((size_t)B_SEG * DIM + B_SEG) * sizeof(float), stream);

    k_wprep<<<DIM, DIM, 0, stream>>>(Wg, Wt);

    int nblk1 = (n + CHUNK - 1) / CHUNK;
    k_segsum<<<nblk1, 256, 0, stream>>>(x, batch, sums, cnt, n);

    k_vn<<<B_SEG, 256, 0, stream>>>(sums, cnt, vn_embed,
                                    W1, b1, g1, be1,
                                    W2, b2, g2, be2,
                                    Wg, bg,
                                    vn_state_out, nu, gpart);

    int nblk3 = (n + BM - 1) / BM;
    k_gate_mfma<<<nblk3, 256, 0, stream>>>(x, batch, Wt, nu, gpart, xout, n);
}

// Round 3
// 319.252 us; speedup vs baseline: 1.5221x; 1.0037x over previous
//
#include <hip/hip_runtime.h>
#include <hip/hip_bf16.h>
#include <math.h>

#define DIM 256
#define B_SEG 512
#define LN_EPS 1e-5f
#define CHUNK 128   // nodes per block in segsum
#define BM 64       // nodes per block in gate kernel

typedef __attribute__((ext_vector_type(8))) short bf16x8;
typedef __attribute__((ext_vector_type(4))) float f32x4;

__device__ __forceinline__ float gelu_exact(float v) {
    return 0.5f * v * (1.0f + erff(v * 0.70710678118654752f));
}

__device__ __forceinline__ bf16x8 cvt8(float4 f0, float4 f1) {
    bf16x8 r;
    r[0] = (short)__bfloat16_as_ushort(__float2bfloat16(f0.x));
    r[1] = (short)__bfloat16_as_ushort(__float2bfloat16(f0.y));
    r[2] = (short)__bfloat16_as_ushort(__float2bfloat16(f0.z));
    r[3] = (short)__bfloat16_as_ushort(__float2bfloat16(f0.w));
    r[4] = (short)__bfloat16_as_ushort(__float2bfloat16(f1.x));
    r[5] = (short)__bfloat16_as_ushort(__float2bfloat16(f1.y));
    r[6] = (short)__bfloat16_as_ushort(__float2bfloat16(f1.z));
    r[7] = (short)__bfloat16_as_ushort(__float2bfloat16(f1.w));
    return r;
}

// ---------------- Kernel 0: transpose+convert Wg top half -> Wt[c][k] bf16 ----
__global__ __launch_bounds__(256) void k_wprep(const float* __restrict__ Wg,
                                               __hip_bfloat16* __restrict__ Wt) {
    int c = blockIdx.x;   // 0..255 (output col)
    int k = threadIdx.x;  // 0..255
    Wt[(size_t)c * DIM + k] = __float2bfloat16(Wg[(size_t)k * DIM + c]);
}

// ---------------- Kernel 1: segment sum + counts (batch sorted, float4) -------
__global__ __launch_bounds__(256) void k_segsum(const float* __restrict__ x,
                                                const int* __restrict__ batch,
                                                float* __restrict__ sums,  // [B,D]
                                                float* __restrict__ cnt,   // [B]
                                                int n) {
    int i0 = blockIdx.x * CHUNK;
    if (i0 >= n) return;
    int i1 = min(i0 + CHUNK, n);
    const int t  = threadIdx.x;
    const int d4 = (t & 63) * 4;   // dim base (float4)
    const int rg = t >> 6;         // row group 0..3

    float4 acc = make_float4(0.f, 0.f, 0.f, 0.f);
    int cur = -1;
    int run = 0;
    for (int i = i0 + rg; i < i1; i += 4) {
        int b = batch[i];
        if (b != cur) {
            if (cur >= 0) {
                atomicAdd(&sums[(size_t)cur * DIM + d4 + 0], acc.x);
                atomicAdd(&sums[(size_t)cur * DIM + d4 + 1], acc.y);
                atomicAdd(&sums[(size_t)cur * DIM + d4 + 2], acc.z);
                atomicAdd(&sums[(size_t)cur * DIM + d4 + 3], acc.w);
                if (d4 == 0) atomicAdd(&cnt[cur], (float)run);
            }
            acc = make_float4(0.f, 0.f, 0.f, 0.f);
            run = 0; cur = b;
        }
        float4 v = *(const float4*)(x + (size_t)i * DIM + d4);
        acc.x += v.x; acc.y += v.y; acc.z += v.z; acc.w += v.w;
        run++;
    }
    if (cur >= 0) {
        atomicAdd(&sums[(size_t)cur * DIM + d4 + 0], acc.x);
        atomicAdd(&sums[(size_t)cur * DIM + d4 + 1], acc.y);
        atomicAdd(&sums[(size_t)cur * DIM + d4 + 2], acc.z);
        atomicAdd(&sums[(size_t)cur * DIM + d4 + 3], acc.w);
        if (d4 == 0) atomicAdd(&cnt[cur], (float)run);
    }
}

// ---------------- Kernel 2: per-segment VN pipeline ---------------------------
__global__ __launch_bounds__(256) void k_vn(const float* __restrict__ sums,
                                            const float* __restrict__ cnt,
                                            const float* __restrict__ vn_embed,
                                            const float* __restrict__ W1, const float* __restrict__ b1,
                                            const float* __restrict__ g1, const float* __restrict__ be1,
                                            const float* __restrict__ W2, const float* __restrict__ b2,
                                            const float* __restrict__ g2, const float* __restrict__ be2,
                                            const float* __restrict__ Wg, const float* __restrict__ bg,
                                            float* __restrict__ vn_state_out, // [B,D]
                                            float* __restrict__ nu,           // ws [B,D]
                                            float* __restrict__ gpart) {      // ws [B,D]
    __shared__ float sIn[DIM];
    __shared__ float sRed[DIM];
    __shared__ float sRed2[DIM];
    const int b = blockIdx.x;
    const int d = threadIdx.x;

    float c = cnt[b];
    float denom = fmaxf(c, 1.0f);
    sIn[d] = sums[(size_t)b * DIM + d] / denom;
    __syncthreads();

    float h = b1[d];
    for (int k = 0; k < DIM; ++k) h = fmaf(sIn[k], W1[(size_t)k * DIM + d], h);
    h = gelu_exact(h);

    sRed[d] = h; sRed2[d] = h * h;
    __syncthreads();
    for (int s = 128; s > 0; s >>= 1) {
        if (d < s) { sRed[d] += sRed[d + s]; sRed2[d] += sRed2[d + s]; }
        __syncthreads();
    }
    float mu = sRed[0] * (1.0f / DIM);
    float var = fmaxf(sRed2[0] * (1.0f / DIM) - mu * mu, 0.0f);
    float rs = rsqrtf(var + LN_EPS);
    float vnst = vn_embed[d] + ((h - mu) * rs * g1[d] + be1[d]);
    vn_state_out[(size_t)b * DIM + d] = vnst;
    __syncthreads();
    sIn[d] = vnst;
    __syncthreads();

    float h2 = b2[d];
    for (int k = 0; k < DIM; ++k) h2 = fmaf(sIn[k], W2[(size_t)k * DIM + d], h2);
    h2 = gelu_exact(h2);

    sRed[d] = h2; sRed2[d] = h2 * h2;
    __syncthreads();
    for (int s = 128; s > 0; s >>= 1) {
        if (d < s) { sRed[d] += sRed[d + s]; sRed2[d] += sRed2[d + s]; }
        __syncthreads();
    }
    float mu2 = sRed[0] * (1.0f / DIM);
    float var2 = fmaxf(sRed2[0] * (1.0f / DIM) - mu2 * mu2, 0.0f);
    float rs2 = rsqrtf(var2 + LN_EPS);
    float nud = (h2 - mu2) * rs2 * g2[d] + be2[d];
    nu[(size_t)b * DIM + d] = nud;
    __syncthreads();
    sIn[d] = nud;
    __syncthreads();

    float gp = bg[d];
    for (int k = 0; k < DIM; ++k) gp = fmaf(sIn[k], Wg[(size_t)(DIM + k) * DIM + d], gp);
    gpart[(size_t)b * DIM + d] = gp;
}

// ---------------- Kernel 3: MFMA gate GEMM, no LDS, no barriers ---------------
// grid: n/BM blocks, 256 threads = 4 waves; wave w -> cols [w*64, w*64+64)
// A frags: direct global fp32 loads + in-reg cvt (tile L2-resident across waves)
// B frags: direct global bf16 loads from Wt (128 KB, L2-resident chip-wide)
__global__ __launch_bounds__(256, 2) void k_gate_mfma(const float* __restrict__ x,
                                                      const int* __restrict__ batch,
                                                      const __hip_bfloat16* __restrict__ Wt, // [256c][256k]
                                                      const float* __restrict__ nu,    // [B,D]
                                                      const float* __restrict__ gpart, // [B,D]
                                                      float* __restrict__ xout,
                                                      int n) {
    const int tid  = threadIdx.x;
    const int wave = tid >> 6;
    const int lane = tid & 63;
    const int i0   = blockIdx.x * BM;
    const int r15  = lane & 15;
    const int kq   = lane >> 4;      // 0..3 : k-subgroup (8 elems each)

    f32x4 acc[4][4];
    #pragma unroll
    for (int m = 0; m < 4; ++m)
        #pragma unroll
        for (int nn = 0; nn < 4; ++nn)
            acc[m][nn] = (f32x4){0.f, 0.f, 0.f, 0.f};

    #pragma unroll 2
    for (int kk = 0; kk < 8; ++kk) {
        const int k0 = kk * 32;
        // B frags from L2-hot Wt
        bf16x8 b[4];
        #pragma unroll
        for (int nn = 0; nn < 4; ++nn) {
            int c = wave * 64 + nn * 16 + r15;
            b[nn] = *(const bf16x8*)(Wt + (size_t)c * DIM + k0 + kq * 8);
        }
        // A frags from global fp32 + cvt
        bf16x8 a[4];
        #pragma unroll
        for (int m = 0; m < 4; ++m) {
            int node = i0 + m * 16 + r15;
            float4 f0, f1;
            if (node < n) {
                const float* p = x + (size_t)node * DIM + k0 + kq * 8;
                f0 = *(const float4*)p;
                f1 = *(const float4*)(p + 4);
            } else {
                f0 = make_float4(0.f, 0.f, 0.f, 0.f);
                f1 = f0;
            }
            a[m] = cvt8(f0, f1);
        }
        #pragma unroll
        for (int m = 0; m < 4; ++m)
            #pragma unroll
            for (int nn = 0; nn < 4; ++nn)
                acc[m][nn] = __builtin_amdgcn_mfma_f32_16x16x32_bf16(a[m], b[nn], acc[m][nn], 0, 0, 0);
    }

    // ---- epilogue: + gpart[seg], sigmoid, x + g*nu ----
    // C layout: col = lane&15, row = (lane>>4)*4 + q   [m89]
    #pragma unroll
    for (int m = 0; m < 4; ++m) {
        #pragma unroll
        for (int q = 0; q < 4; ++q) {
            int rr = m * 16 + kq * 4 + q;
            int node = i0 + rr;
            if (node >= n) continue;
            int bb = batch[node];
            #pragma unroll
            for (int nn = 0; nn < 4; ++nn) {
                int col = wave * 64 + nn * 16 + r15;
                float pre = acc[m][nn][q] + gpart[bb * DIM + col];
                float gte = 1.0f / (1.0f + expf(-pre));
                xout[(size_t)node * DIM + col] = x[(size_t)node * DIM + col] + gte * nu[bb * DIM + col];
            }
        }
    }
}

extern "C" void kernel_launch(void* const* d_in, const int* in_sizes, int n_in,
                              void* d_out, int out_size, void* d_ws, size_t ws_size,
                              hipStream_t stream) {
    const float* x        = (const float*)d_in[0];
    const int*   batch    = (const int*)d_in[1];
    const float* vn_embed = (const float*)d_in[2];
    const float* W1  = (const float*)d_in[3];
    const float* b1  = (const float*)d_in[4];
    const float* g1  = (const float*)d_in[5];
    const float* be1 = (const float*)d_in[6];
    const float* W2  = (const float*)d_in[7];
    const float* b2  = (const float*)d_in[8];
    const float* g2  = (const float*)d_in[9];
    const float* be2 = (const float*)d_in[10];
    const float* Wg  = (const float*)d_in[11];
    const float* bg  = (const float*)d_in[12];

    const int n = in_sizes[0] / DIM;

    float* out = (float*)d_out;
    float* xout = out;                              // [N,D]
    float* vn_state_out = out + (size_t)n * DIM;    // [B,D]

    float* ws    = (float*)d_ws;
    float* sums  = ws;                                   // B*D
    float* cnt   = sums + (size_t)B_SEG * DIM;           // B
    float* nu    = cnt + B_SEG;                          // B*D
    float* gpart = nu + (size_t)B_SEG * DIM;             // B*D
    __hip_bfloat16* Wt = (__hip_bfloat16*)(gpart + (size_t)B_SEG * DIM); // 256*256 bf16

    hipMemsetAsync(d_ws, 0, ((size_t)B_SEG * DIM + B_SEG) * sizeof(float), stream);

    k_wprep<<<DIM, DIM, 0, stream>>>(Wg, Wt);

    int nblk1 = (n + CHUNK - 1) / CHUNK;
    k_segsum<<<nblk1, 256, 0, stream>>>(x, batch, sums, cnt, n);

    k_vn<<<B_SEG, 256, 0, stream>>>(sums, cnt, vn_embed,
                                    W1, b1, g1, be1,
                                    W2, b2, g2, be2,
                                    Wg, bg,
                                    vn_state_out, nu, gpart);

    int nblk3 = (n + BM - 1) / BM;
    k_gate_mfma<<<nblk3, 256, 0, stream>>>(x, batch, Wt, nu, gpart, xout, n);
}

// Round 4
// 277.975 us; speedup vs baseline: 1.7481x; 1.1485x over previous
//
#include <hip/hip_runtime.h>
#include <hip/hip_bf16.h>
#include <math.h>

#define DIM 256
#define B_SEG 512
#define LN_EPS 1e-5f
#define CHUNK 64    // nodes per block in segsum
#define BM 64       // nodes per block in gate kernel

typedef __attribute__((ext_vector_type(8))) short bf16x8;
typedef __attribute__((ext_vector_type(4))) float f32x4;

__device__ __forceinline__ float gelu_exact(float v) {
    return 0.5f * v * (1.0f + erff(v * 0.70710678118654752f));
}

__device__ __forceinline__ unsigned int pack2bf(float a, float b) {
    unsigned int ua = (unsigned int)__bfloat16_as_ushort(__float2bfloat16(a));
    unsigned int ub = (unsigned int)__bfloat16_as_ushort(__float2bfloat16(b));
    return ua | (ub << 16);
}

// ---------------- Kernel 0: transpose+convert Wg top half -> Wt[c][k] bf16 ----
__global__ __launch_bounds__(256) void k_wprep(const float* __restrict__ Wg,
                                               __hip_bfloat16* __restrict__ Wt) {
    int c = blockIdx.x;   // 0..255 (output col)
    int k = threadIdx.x;  // 0..255
    Wt[(size_t)c * DIM + k] = __float2bfloat16(Wg[(size_t)k * DIM + c]);
}

// ---------------- Kernel 1: segment sum + counts (batch sorted, float4) -------
__global__ __launch_bounds__(256) void k_segsum(const float* __restrict__ x,
                                                const int* __restrict__ batch,
                                                float* __restrict__ sums,  // [B,D]
                                                float* __restrict__ cnt,   // [B]
                                                int n) {
    int i0 = blockIdx.x * CHUNK;
    if (i0 >= n) return;
    int i1 = min(i0 + CHUNK, n);
    const int t  = threadIdx.x;
    const int d4 = (t & 63) * 4;   // dim base (float4)
    const int rg = t >> 6;         // row group 0..3

    float4 acc = make_float4(0.f, 0.f, 0.f, 0.f);
    int cur = -1;
    int run = 0;
    for (int i = i0 + rg; i < i1; i += 4) {
        int b = batch[i];
        if (b != cur) {
            if (cur >= 0) {
                atomicAdd(&sums[(size_t)cur * DIM + d4 + 0], acc.x);
                atomicAdd(&sums[(size_t)cur * DIM + d4 + 1], acc.y);
                atomicAdd(&sums[(size_t)cur * DIM + d4 + 2], acc.z);
                atomicAdd(&sums[(size_t)cur * DIM + d4 + 3], acc.w);
                if (d4 == 0) atomicAdd(&cnt[cur], (float)run);
            }
            acc = make_float4(0.f, 0.f, 0.f, 0.f);
            run = 0; cur = b;
        }
        float4 v = *(const float4*)(x + (size_t)i * DIM + d4);
        acc.x += v.x; acc.y += v.y; acc.z += v.z; acc.w += v.w;
        run++;
    }
    if (cur >= 0) {
        atomicAdd(&sums[(size_t)cur * DIM + d4 + 0], acc.x);
        atomicAdd(&sums[(size_t)cur * DIM + d4 + 1], acc.y);
        atomicAdd(&sums[(size_t)cur * DIM + d4 + 2], acc.z);
        atomicAdd(&sums[(size_t)cur * DIM + d4 + 3], acc.w);
        if (d4 == 0) atomicAdd(&cnt[cur], (float)run);
    }
}

// ---------------- Kernel 2: per-segment VN pipeline ---------------------------
__global__ __launch_bounds__(256) void k_vn(const float* __restrict__ sums,
                                            const float* __restrict__ cnt,
                                            const float* __restrict__ vn_embed,
                                            const float* __restrict__ W1, const float* __restrict__ b1,
                                            const float* __restrict__ g1, const float* __restrict__ be1,
                                            const float* __restrict__ W2, const float* __restrict__ b2,
                                            const float* __restrict__ g2, const float* __restrict__ be2,
                                            const float* __restrict__ Wg, const float* __restrict__ bg,
                                            float* __restrict__ vn_state_out, // [B,D]
                                            float* __restrict__ nu,           // ws [B,D]
                                            float* __restrict__ gpart) {      // ws [B,D]
    __shared__ float sIn[DIM];
    __shared__ float sRed[DIM];
    __shared__ float sRed2[DIM];
    const int b = blockIdx.x;
    const int d = threadIdx.x;

    float c = cnt[b];
    float denom = fmaxf(c, 1.0f);
    sIn[d] = sums[(size_t)b * DIM + d] / denom;
    __syncthreads();

    float h = b1[d];
    for (int k = 0; k < DIM; ++k) h = fmaf(sIn[k], W1[(size_t)k * DIM + d], h);
    h = gelu_exact(h);

    sRed[d] = h; sRed2[d] = h * h;
    __syncthreads();
    for (int s = 128; s > 0; s >>= 1) {
        if (d < s) { sRed[d] += sRed[d + s]; sRed2[d] += sRed2[d + s]; }
        __syncthreads();
    }
    float mu = sRed[0] * (1.0f / DIM);
    float var = fmaxf(sRed2[0] * (1.0f / DIM) - mu * mu, 0.0f);
    float rs = rsqrtf(var + LN_EPS);
    float vnst = vn_embed[d] + ((h - mu) * rs * g1[d] + be1[d]);
    vn_state_out[(size_t)b * DIM + d] = vnst;
    __syncthreads();
    sIn[d] = vnst;
    __syncthreads();

    float h2 = b2[d];
    for (int k = 0; k < DIM; ++k) h2 = fmaf(sIn[k], W2[(size_t)k * DIM + d], h2);
    h2 = gelu_exact(h2);

    sRed[d] = h2; sRed2[d] = h2 * h2;
    __syncthreads();
    for (int s = 128; s > 0; s >>= 1) {
        if (d < s) { sRed[d] += sRed[d + s]; sRed2[d] += sRed2[d + s]; }
        __syncthreads();
    }
    float mu2 = sRed[0] * (1.0f / DIM);
    float var2 = fmaxf(sRed2[0] * (1.0f / DIM) - mu2 * mu2, 0.0f);
    float rs2 = rsqrtf(var2 + LN_EPS);
    float nud = (h2 - mu2) * rs2 * g2[d] + be2[d];
    nu[(size_t)b * DIM + d] = nud;
    __syncthreads();
    sIn[d] = nud;
    __syncthreads();

    float gp = bg[d];
    for (int k = 0; k < DIM; ++k) gp = fmaf(sIn[k], Wg[(size_t)(DIM + k) * DIM + d], gp);
    gpart[(size_t)b * DIM + d] = gp;
}

// ---------------- Kernel 3: MFMA gate GEMM, full-K LDS A-tile, one barrier ----
// grid: n/BM blocks, 256 threads = 4 waves; wave w -> cols [w*64, w*64+64)
// A: 64x256 bf16 tile in LDS (XOR-swizzled), staged via 16 independent float4
//    loads per thread (T14 split: issue all, then cvt+ds_write). Single barrier.
// B: direct global bf16 loads from Wt (128 KB, L2-resident chip-wide).
// Inter-block overlap (3-4 blocks/CU @ 32KB LDS) pipelines staging vs compute.
__global__ __launch_bounds__(256) void k_gate_mfma(const float* __restrict__ x,
                                                   const int* __restrict__ batch,
                                                   const __hip_bfloat16* __restrict__ Wt, // [256c][256k]
                                                   const float* __restrict__ nu,    // [B,D]
                                                   const float* __restrict__ gpart, // [B,D]
                                                   float* __restrict__ xout,
                                                   int n) {
    __shared__ __align__(16) char sA[BM * 512];   // 32 KB: [r][k] bf16, swizzled

    const int tid  = threadIdx.x;
    const int wave = tid >> 6;
    const int lane = tid & 63;
    const int i0   = blockIdx.x * BM;
    const int r15  = lane & 15;
    const int kq   = lane >> 4;      // 0..3 : k-subgroup (8 elems each)

    // ---- stage A: issue all 16 float4 loads first (max MLP), then cvt+write ----
    float4 av0[8], av1[8];
    #pragma unroll
    for (int j = 0; j < 8; ++j) {
        int v = j * 256 + tid;       // float8-group index, 0..2047
        int r = v >> 5;              // row 0..63
        int k8 = v & 31;             // 8-float k-group
        int node = i0 + r;
        if (node < n) {
            const float* p = x + (size_t)node * DIM + k8 * 8;
            av0[j] = *(const float4*)p;
            av1[j] = *(const float4*)(p + 4);
        } else {
            av0[j] = make_float4(0.f, 0.f, 0.f, 0.f);
            av1[j] = av0[j];
        }
    }
    #pragma unroll
    for (int j = 0; j < 8; ++j) {
        int v = j * 256 + tid;
        int r = v >> 5;
        int k8 = v & 31;
        uint4 pk;
        pk.x = pack2bf(av0[j].x, av0[j].y);
        pk.y = pack2bf(av0[j].z, av0[j].w);
        pk.z = pack2bf(av1[j].x, av1[j].y);
        pk.w = pack2bf(av1[j].z, av1[j].w);
        *(uint4*)(sA + r * 512 + ((k8 * 16) ^ ((r & 7) << 4))) = pk;
    }
    __syncthreads();

    f32x4 acc[4][4];
    #pragma unroll
    for (int m = 0; m < 4; ++m)
        #pragma unroll
        for (int nn = 0; nn < 4; ++nn)
            acc[m][nn] = (f32x4){0.f, 0.f, 0.f, 0.f};

    #pragma unroll
    for (int ks = 0; ks < 8; ++ks) {
        bf16x8 a[4], b[4];
        #pragma unroll
        for (int nn = 0; nn < 4; ++nn) {
            int c = wave * 64 + nn * 16 + r15;
            b[nn] = *(const bf16x8*)(Wt + (size_t)c * DIM + ks * 32 + kq * 8);
        }
        #pragma unroll
        for (int m = 0; m < 4; ++m) {
            int r = m * 16 + r15;
            a[m] = *(const bf16x8*)(sA + r * 512 + ((ks * 64 + kq * 16) ^ ((r & 7) << 4)));
        }
        #pragma unroll
        for (int m = 0; m < 4; ++m)
            #pragma unroll
            for (int nn = 0; nn < 4; ++nn)
                acc[m][nn] = __builtin_amdgcn_mfma_f32_16x16x32_bf16(a[m], b[nn], acc[m][nn], 0, 0, 0);
    }

    // ---- epilogue: + gpart[seg], sigmoid, x + g*nu ----
    // C layout: col = lane&15, row = (lane>>4)*4 + q   [m89]
    #pragma unroll
    for (int m = 0; m < 4; ++m) {
        #pragma unroll
        for (int q = 0; q < 4; ++q) {
            int rr = m * 16 + kq * 4 + q;
            int node = i0 + rr;
            if (node >= n) continue;
            int bb = batch[node];
            #pragma unroll
            for (int nn = 0; nn < 4; ++nn) {
                int col = wave * 64 + nn * 16 + r15;
                float pre = acc[m][nn][q] + gpart[bb * DIM + col];
                float gte = 1.0f / (1.0f + expf(-pre));
                xout[(size_t)node * DIM + col] = x[(size_t)node * DIM + col] + gte * nu[bb * DIM + col];
            }
        }
    }
}

extern "C" void kernel_launch(void* const* d_in, const int* in_sizes, int n_in,
                              void* d_out, int out_size, void* d_ws, size_t ws_size,
                              hipStream_t stream) {
    const float* x        = (const float*)d_in[0];
    const int*   batch    = (const int*)d_in[1];
    const float* vn_embed = (const float*)d_in[2];
    const float* W1  = (const float*)d_in[3];
    const float* b1  = (const float*)d_in[4];
    const float* g1  = (const float*)d_in[5];
    const float* be1 = (const float*)d_in[6];
    const float* W2  = (const float*)d_in[7];
    const float* b2  = (const float*)d_in[8];
    const float* g2  = (const float*)d_in[9];
    const float* be2 = (const float*)d_in[10];
    const float* Wg  = (const float*)d_in[11];
    const float* bg  = (const float*)d_in[12];

    const int n = in_sizes[0] / DIM;

    float* out = (float*)d_out;
    float* xout = out;                              // [N,D]
    float* vn_state_out = out + (size_t)n * DIM;    // [B,D]

    float* ws    = (float*)d_ws;
    float* sums  = ws;                                   // B*D
    float* cnt   = sums + (size_t)B_SEG * DIM;           // B
    float* nu    = cnt + B_SEG;                          // B*D
    float* gpart = nu + (size_t)B_SEG * DIM;             // B*D
    __hip_bfloat16* Wt = (__hip_bfloat16*)(gpart + (size_t)B_SEG * DIM); // 256*256 bf16

    hipMemsetAsync(d_ws, 0, ((size_t)B_SEG * DIM + B_SEG) * sizeof(float), stream);

    k_wprep<<<DIM, DIM, 0, stream>>>(Wg, Wt);

    int nblk1 = (n + CHUNK - 1) / CHUNK;
    k_segsum<<<nblk1, 256, 0, stream>>>(x, batch, sums, cnt, n);

    k_vn<<<B_SEG, 256, 0, stream>>>(sums, cnt, vn_embed,
                                    W1, b1, g1, be1,
                                    W2, b2, g2, be2,
                                    Wg, bg,
                                    vn_state_out, nu, gpart);

    int nblk3 = (n + BM - 1) / BM;
    k_gate_mfma<<<nblk3, 256, 0, stream>>>(x, batch, Wt, nu, gpart, xout, n);
}